// Round 1
// baseline (85.855 us; speedup 1.0000x reference)
//
#include <hip/hip_runtime.h>

// Quanvolution: 8-qubit state-vector sim per 2x2 patch.
// One wave (64 lanes) per output pixel (b,i,j); loops ch=0..2.
// State: 256 complex amps = 4 complex per lane.
//   amp index n = (lane << 2) | r ; qubit q == bit q of n.
//   qubits 0,1 = local bits (r), qubits 2..7 = lane bits.

namespace {

// RX butterfly on local qubit 0: pairs (r0,r1),(r2,r3)
__device__ __forceinline__ void rx_l0(float (&sr)[4], float (&si)[4], float c, float s) {
    float nr0 = c*sr[0] + s*si[1], ni0 = c*si[0] - s*sr[1];
    float nr1 = c*sr[1] + s*si[0], ni1 = c*si[1] - s*sr[0];
    float nr2 = c*sr[2] + s*si[3], ni2 = c*si[2] - s*sr[3];
    float nr3 = c*sr[3] + s*si[2], ni3 = c*si[3] - s*sr[2];
    sr[0]=nr0; si[0]=ni0; sr[1]=nr1; si[1]=ni1;
    sr[2]=nr2; si[2]=ni2; sr[3]=nr3; si[3]=ni3;
}

// RX butterfly on local qubit 1: pairs (r0,r2),(r1,r3)
__device__ __forceinline__ void rx_l1(float (&sr)[4], float (&si)[4], float c, float s) {
    float nr0 = c*sr[0] + s*si[2], ni0 = c*si[0] - s*sr[2];
    float nr2 = c*sr[2] + s*si[0], ni2 = c*si[2] - s*sr[0];
    float nr1 = c*sr[1] + s*si[3], ni1 = c*si[1] - s*sr[3];
    float nr3 = c*sr[3] + s*si[1], ni3 = c*si[3] - s*sr[1];
    sr[0]=nr0; si[0]=ni0; sr[1]=nr1; si[1]=ni1;
    sr[2]=nr2; si[2]=ni2; sr[3]=nr3; si[3]=ni3;
}

// RX butterfly on lane-qubit (lane-bit mask). Symmetric: same formula
// for both halves of each pair -> no divergence.
__device__ __forceinline__ void rx_lane(float (&sr)[4], float (&si)[4], float c, float s, int mask) {
#pragma unroll
    for (int r = 0; r < 4; ++r) {
        float orr = __shfl_xor(sr[r], mask, 64);
        float oii = __shfl_xor(si[r], mask, 64);
        float nr = c*sr[r] + s*oii;
        float ni = c*si[r] - s*orr;
        sr[r] = nr; si[r] = ni;
    }
}

} // namespace

#define NWAVES (8*39*39)  // 12168, divisible by 4

__global__ __launch_bounds__(256) void quanv_kernel(
    const float* __restrict__ x,   // (8,3,40,40)
    const float* __restrict__ w,   // (2,8)
    float* __restrict__ out)       // (8,2,39,39)
{
    const int wid  = (int)(blockIdx.x * 4 + (threadIdx.x >> 6));
    const int lane = (int)(threadIdx.x & 63);
    if (wid >= NWAVES) return;

    const int j = wid % 39;
    const int t = wid / 39;
    const int i = t % 39;
    const int b = t / 39;

    // half-angle cos/sin of the 16 weight angles (shared by all patches)
    float wc[16], ws[16];
#pragma unroll
    for (int k = 0; k < 16; ++k) __sincosf(0.5f * w[k], &ws[k], &wc[k]);

    float z0 = 0.f, z1 = 0.f;

    for (int ch = 0; ch < 3; ++ch) {
        const float* xp = x + (((b*3 + ch)*40) + i)*40 + j;
        const float f0 = xp[0], f1 = xp[1], f2 = xp[40], f3 = xp[41];

        // |0...0>
        float sr[4], si[4];
        sr[0] = (lane == 0) ? 1.f : 0.f; si[0] = 0.f;
        sr[1] = 0.f; si[1] = 0.f;
        sr[2] = 0.f; si[2] = 0.f;
        sr[3] = 0.f; si[3] = 0.f;

        float c, s;
        // AngleEmbedding: RX(f_i) on wires 0..3
        __sincosf(0.5f*f0, &s, &c); rx_l0(sr, si, c, s);
        __sincosf(0.5f*f1, &s, &c); rx_l1(sr, si, c, s);
        __sincosf(0.5f*f2, &s, &c); rx_lane(sr, si, c, s, 1);
        __sincosf(0.5f*f3, &s, &c); rx_lane(sr, si, c, s, 2);

        // BasicEntanglerLayers
#pragma unroll
        for (int l = 0; l < 2; ++l) {
            rx_l0(sr, si, wc[l*8+0], ws[l*8+0]);
            rx_l1(sr, si, wc[l*8+1], ws[l*8+1]);
#pragma unroll
            for (int q = 2; q < 8; ++q)
                rx_lane(sr, si, wc[l*8+q], ws[l*8+q], 1 << (q-2));

            // CNOT(0,1): amps with b0=1 flip b1 -> swap r1<->r3
            { float tr=sr[1], ti=si[1]; sr[1]=sr[3]; si[1]=si[3]; sr[3]=tr; si[3]=ti; }

            // CNOT(1,2): amps with b1=1 (r=2,3) flip lane-bit0
            sr[2] = __shfl_xor(sr[2], 1, 64); si[2] = __shfl_xor(si[2], 1, 64);
            sr[3] = __shfl_xor(sr[3], 1, 64); si[3] = __shfl_xor(si[3], 1, 64);

            // CNOT(q,q+1), q=2..6: control lane-bit (q-2), target lane-bit (q-1)
#pragma unroll
            for (int q = 2; q <= 6; ++q) {
                const int mt = 1 << (q-1);
                const bool ctrl = (lane >> (q-2)) & 1;
#pragma unroll
                for (int r = 0; r < 4; ++r) {
                    float orr = __shfl_xor(sr[r], mt, 64);
                    float oii = __shfl_xor(si[r], mt, 64);
                    sr[r] = ctrl ? orr : sr[r];
                    si[r] = ctrl ? oii : si[r];
                }
            }

            // CNOT(7,0): lanes with bit5=1 swap (r0<->r1),(r2<->r3)
            {
                const bool ctrl = (lane >> 5) & 1;
                float a0 = ctrl ? sr[1] : sr[0], b0 = ctrl ? si[1] : si[0];
                float a1 = ctrl ? sr[0] : sr[1], b1 = ctrl ? si[0] : si[1];
                float a2 = ctrl ? sr[3] : sr[2], b2 = ctrl ? si[3] : si[2];
                float a3 = ctrl ? sr[2] : sr[3], b3 = ctrl ? si[2] : si[3];
                sr[0]=a0; si[0]=b0; sr[1]=a1; si[1]=b1;
                sr[2]=a2; si[2]=b2; sr[3]=a3; si[3]=b3;
            }
        }

        // <Z0>, <Z1> per-lane partial sums (b0 = r&1, b1 = r>>1)
        const float p0 = sr[0]*sr[0] + si[0]*si[0];
        const float p1 = sr[1]*sr[1] + si[1]*si[1];
        const float p2 = sr[2]*sr[2] + si[2]*si[2];
        const float p3 = sr[3]*sr[3] + si[3]*si[3];
        z0 += (p0 - p1) + (p2 - p3);
        z1 += (p0 + p1) - (p2 + p3);
    }

    // wave reduction
#pragma unroll
    for (int m = 1; m < 64; m <<= 1) {
        z0 += __shfl_xor(z0, m, 64);
        z1 += __shfl_xor(z1, m, 64);
    }

    if (lane == 0) {
        const float inv_ch = (1.f/3.f);
        out[((b*2 + 0)*39 + i)*39 + j] = z0 * inv_ch;
        out[((b*2 + 1)*39 + i)*39 + j] = z1 * inv_ch;
    }
}

extern "C" void kernel_launch(void* const* d_in, const int* in_sizes, int n_in,
                              void* d_out, int out_size, void* d_ws, size_t ws_size,
                              hipStream_t stream) {
    const float* x = (const float*)d_in[0];
    const float* w = (const float*)d_in[1];
    float* out = (float*)d_out;

    const int nblocks = NWAVES / 4;  // 4 waves (256 threads) per block
    quanv_kernel<<<nblocks, 256, 0, stream>>>(x, w, out);
}

// Round 2
// 56.773 us; speedup vs baseline: 1.5123x; 1.5123x over previous
//
#include <hip/hip_runtime.h>

// Quanvolution: 8-qubit state-vector sim per 2x2 patch.
// Qubit mapping: q0..q3 = LOCAL bits (16 complex amps/lane),
//                q4..q7 = lane bits 0..3 (16 lanes per circuit).
// 4 circuits per wave (lane bits 4..5 = circuit group).
// One circuit = one (b, ch, pixel); channel mean via atomicAdd (out pre-zeroed).

namespace {

// RX on local qubit with mask M (1,2,4,8). Pure register math.
template<int M>
__device__ __forceinline__ void rx_local(float (&sr)[16], float (&si)[16], float c, float s) {
#pragma unroll
    for (int r = 0; r < 16; ++r) {
        if (r & M) continue;
        const int a = r, b = r | M;
        float nra = c*sr[a] + s*si[b], nia = c*si[a] - s*sr[b];
        float nrb = c*sr[b] + s*si[a], nib = c*si[b] - s*sr[a];
        sr[a]=nra; si[a]=nia; sr[b]=nrb; si[b]=nib;
    }
}

// RX on lane qubit (xor mask). Symmetric butterfly, no divergence.
__device__ __forceinline__ void rx_lane16(float (&sr)[16], float (&si)[16], float c, float s, int mask) {
#pragma unroll
    for (int r = 0; r < 16; ++r) {
        float orr = __shfl_xor(sr[r], mask, 64);
        float oii = __shfl_xor(si[r], mask, 64);
        sr[r] = c*sr[r] + s*oii;
        si[r] = c*si[r] - s*orr;
    }
}

// CNOT local->local: compile-time register permutation (free).
template<int C, int T>
__device__ __forceinline__ void cnot_ll(float (&sr)[16], float (&si)[16]) {
#pragma unroll
    for (int r = 0; r < 16; ++r) {
        if (!(r & C) || (r & T)) continue;   // bitC=1, bitT=0: visit each pair once
        const int a = r, b = r ^ T;
        float tr=sr[a], ti=si[a];
        sr[a]=sr[b]; si[a]=si[b];
        sr[b]=tr;    si[b]=ti;
    }
}

} // namespace

#define NCIRC (8*3*39*39)   // 36504
#define NWAVE (NCIRC/4)     // 9126

__global__ __launch_bounds__(256) void quanv_kernel(
    const float* __restrict__ x,   // (8,3,40,40) fp32
    const float* __restrict__ w,   // (2,8) fp32
    float* __restrict__ out)       // (8,2,39,39) fp32, pre-zeroed
{
    const int wid  = (int)(blockIdx.x * 4 + (threadIdx.x >> 6));
    const int lane = (int)(threadIdx.x & 63);
    if (wid >= NWAVE) return;

    // circuit id for this lane's group
    const int g   = wid * 4 + (lane >> 4);
    const int pix = g % 1521;            // 39*39
    const int bc  = g / 1521;            // 0..23
    const int ch  = bc % 3;
    const int b   = bc / 3;
    const int i   = pix / 39;
    const int j   = pix % 39;

    // patch values
    const float* xp = x + (((b*3 + ch)*40) + i)*40 + j;
    const float f0 = xp[0], f1 = xp[1], f2 = xp[40], f3 = xp[41];

    // |0...0>: amp 0 lives at lane-group-base, r=0
    float sr[16], si[16];
#pragma unroll
    for (int r = 0; r < 16; ++r) { sr[r] = 0.f; si[r] = 0.f; }
    sr[0] = ((lane & 15) == 0) ? 1.f : 0.f;

    float c, s;
    // AngleEmbedding: RX(f_k) on wires 0..3 -- all local, shuffle-free
    __sincosf(0.5f*f0, &s, &c); rx_local<1>(sr, si, c, s);
    __sincosf(0.5f*f1, &s, &c); rx_local<2>(sr, si, c, s);
    __sincosf(0.5f*f2, &s, &c); rx_local<4>(sr, si, c, s);
    __sincosf(0.5f*f3, &s, &c); rx_local<8>(sr, si, c, s);

    // BasicEntanglerLayers
#pragma unroll
    for (int l = 0; l < 2; ++l) {
        // RX on all 8 wires
        __sincosf(0.5f*w[l*8+0], &s, &c); rx_local<1>(sr, si, c, s);
        __sincosf(0.5f*w[l*8+1], &s, &c); rx_local<2>(sr, si, c, s);
        __sincosf(0.5f*w[l*8+2], &s, &c); rx_local<4>(sr, si, c, s);
        __sincosf(0.5f*w[l*8+3], &s, &c); rx_local<8>(sr, si, c, s);
        __sincosf(0.5f*w[l*8+4], &s, &c); rx_lane16(sr, si, c, s, 1);
        __sincosf(0.5f*w[l*8+5], &s, &c); rx_lane16(sr, si, c, s, 2);
        __sincosf(0.5f*w[l*8+6], &s, &c); rx_lane16(sr, si, c, s, 4);
        __sincosf(0.5f*w[l*8+7], &s, &c); rx_lane16(sr, si, c, s, 8);

        // CNOT ring
        cnot_ll<1,2>(sr, si);   // (0,1)
        cnot_ll<2,4>(sr, si);   // (1,2)
        cnot_ll<4,8>(sr, si);   // (2,3)

        // (3,4): control local b3, target lane b0 -> unconditional swap across lane^1 for r>=8
#pragma unroll
        for (int r = 8; r < 16; ++r) {
            sr[r] = __shfl_xor(sr[r], 1, 64);
            si[r] = __shfl_xor(si[r], 1, 64);
        }

        // (4,5),(5,6),(6,7): control lane bit c, target lane bit c+1
#pragma unroll
        for (int q = 0; q < 3; ++q) {
            const int mt = 2 << q;
            const bool ctrl = (lane >> q) & 1;
#pragma unroll
            for (int r = 0; r < 16; ++r) {
                float orr = __shfl_xor(sr[r], mt, 64);
                float oii = __shfl_xor(si[r], mt, 64);
                sr[r] = ctrl ? orr : sr[r];
                si[r] = ctrl ? oii : si[r];
            }
        }

        // (7,0): control lane b3, target local b0 -> conditional register pair swap
        {
            const bool c7 = (lane >> 3) & 1;
#pragma unroll
            for (int r = 0; r < 16; r += 2) {
                float ar = c7 ? sr[r+1] : sr[r];
                float ai = c7 ? si[r+1] : si[r];
                float br = c7 ? sr[r]   : sr[r+1];
                float bi = c7 ? si[r]   : si[r+1];
                sr[r]=ar; si[r]=ai; sr[r+1]=br; si[r+1]=bi;
            }
        }
    }

    // <Z0>, <Z1>: sign by local bits 0,1
    float z0 = 0.f, z1 = 0.f;
#pragma unroll
    for (int r = 0; r < 16; ++r) {
        const float p = sr[r]*sr[r] + si[r]*si[r];
        z0 += (r & 1) ? -p : p;
        z1 += (r & 2) ? -p : p;
    }

    // reduce across the 16 lanes of the group
#pragma unroll
    for (int m = 1; m < 16; m <<= 1) {
        z0 += __shfl_xor(z0, m, 64);
        z1 += __shfl_xor(z1, m, 64);
    }

    if ((lane & 15) == 0) {
        const float inv_ch = (1.f/3.f);
        atomicAdd(&out[((b*2 + 0)*39 + i)*39 + j], z0 * inv_ch);
        atomicAdd(&out[((b*2 + 1)*39 + i)*39 + j], z1 * inv_ch);
    }
}

extern "C" void kernel_launch(void* const* d_in, const int* in_sizes, int n_in,
                              void* d_out, int out_size, void* d_ws, size_t ws_size,
                              hipStream_t stream) {
    const float* x = (const float*)d_in[0];
    const float* w = (const float*)d_in[1];
    float* out = (float*)d_out;

    hipMemsetAsync(out, 0, (size_t)out_size * sizeof(float), stream);

    const int nblocks = (NWAVE + 3) / 4;  // 4 waves (256 threads) per block
    quanv_kernel<<<nblocks, 256, 0, stream>>>(x, w, out);
}

// Round 3
// 23.316 us; speedup vs baseline: 3.6823x; 2.4350x over previous
//
#include <hip/hip_runtime.h>

// Quanvolution via operator precomputation.
// z_q(f0..f3) = <psi|U^dag Z_q U|psi>, psi = RX-embedded product state.
// Since U (entangler) is data-independent and <X>=0 for RX(f)|0>,
//   z_q = sum_{p in {I,Y,Z}^4} T_q[p] * prod_k v_k(p_k),
//   v_k = (1, -sin f_k, cos f_k).
// Setup kernel (1 block): 16 basis sims -> M_q = U^dag Z_q U (16x16 block)
//   -> Pauli transform -> T_q[81] into d_ws.
// Main kernel: 1 thread per output pixel, 3-channel loop, pure FMA.

namespace {

// ---- verified wave-sim gate helpers (16 local amps, qubits 0-3 local,
// ---- qubits 4-7 = lane bits 0-3, 4 circuits per wave) ----

template<int M>
__device__ __forceinline__ void rx_local(float (&sr)[16], float (&si)[16], float c, float s) {
#pragma unroll
    for (int r = 0; r < 16; ++r) {
        if (r & M) continue;
        const int a = r, b = r | M;
        float nra = c*sr[a] + s*si[b], nia = c*si[a] - s*sr[b];
        float nrb = c*sr[b] + s*si[a], nib = c*si[b] - s*sr[a];
        sr[a]=nra; si[a]=nia; sr[b]=nrb; si[b]=nib;
    }
}

__device__ __forceinline__ void rx_lane16(float (&sr)[16], float (&si)[16], float c, float s, int mask) {
#pragma unroll
    for (int r = 0; r < 16; ++r) {
        float orr = __shfl_xor(sr[r], mask, 64);
        float oii = __shfl_xor(si[r], mask, 64);
        sr[r] = c*sr[r] + s*oii;
        si[r] = c*si[r] - s*orr;
    }
}

template<int C, int T>
__device__ __forceinline__ void cnot_ll(float (&sr)[16], float (&si)[16]) {
#pragma unroll
    for (int r = 0; r < 16; ++r) {
        if (!(r & C) || (r & T)) continue;
        const int a = r, b = r ^ T;
        float tr=sr[a], ti=si[a];
        sr[a]=sr[b]; si[a]=si[b];
        sr[b]=tr;    si[b]=ti;
    }
}

__device__ __forceinline__ void entangler(float (&sr)[16], float (&si)[16],
                                          const float* __restrict__ w, int lane) {
    float c, s;
#pragma unroll
    for (int l = 0; l < 2; ++l) {
        __sincosf(0.5f*w[l*8+0], &s, &c); rx_local<1>(sr, si, c, s);
        __sincosf(0.5f*w[l*8+1], &s, &c); rx_local<2>(sr, si, c, s);
        __sincosf(0.5f*w[l*8+2], &s, &c); rx_local<4>(sr, si, c, s);
        __sincosf(0.5f*w[l*8+3], &s, &c); rx_local<8>(sr, si, c, s);
        __sincosf(0.5f*w[l*8+4], &s, &c); rx_lane16(sr, si, c, s, 1);
        __sincosf(0.5f*w[l*8+5], &s, &c); rx_lane16(sr, si, c, s, 2);
        __sincosf(0.5f*w[l*8+6], &s, &c); rx_lane16(sr, si, c, s, 4);
        __sincosf(0.5f*w[l*8+7], &s, &c); rx_lane16(sr, si, c, s, 8);

        cnot_ll<1,2>(sr, si);   // (0,1)
        cnot_ll<2,4>(sr, si);   // (1,2)
        cnot_ll<4,8>(sr, si);   // (2,3)
        // (3,4): control local b3, target lane b0
#pragma unroll
        for (int r = 8; r < 16; ++r) {
            sr[r] = __shfl_xor(sr[r], 1, 64);
            si[r] = __shfl_xor(si[r], 1, 64);
        }
        // (4,5),(5,6),(6,7)
#pragma unroll
        for (int qq = 0; qq < 3; ++qq) {
            const int mt = 2 << qq;
            const bool ctrl = (lane >> qq) & 1;
#pragma unroll
            for (int r = 0; r < 16; ++r) {
                float orr = __shfl_xor(sr[r], mt, 64);
                float oii = __shfl_xor(si[r], mt, 64);
                sr[r] = ctrl ? orr : sr[r];
                si[r] = ctrl ? oii : si[r];
            }
        }
        // (7,0): control lane b3, target local b0
        {
            const bool c7 = (lane >> 3) & 1;
#pragma unroll
            for (int r = 0; r < 16; r += 2) {
                float ar = c7 ? sr[r+1] : sr[r];
                float ai = c7 ? si[r+1] : si[r];
                float br = c7 ? sr[r]   : sr[r+1];
                float bi = c7 ? si[r]   : si[r+1];
                sr[r]=ar; si[r]=ai; sr[r+1]=br; si[r+1]=bi;
            }
        }
    }
}

// padded LDS index for U[n][g] (avoids 16-way bank conflicts)
__device__ __forceinline__ int uidx(int n, int g) { return n*16 + g + (n>>4); }

} // namespace

// ---------------- setup: T_q[81] from weights ----------------
__global__ __launch_bounds__(256) void quanv_setup(const float* __restrict__ w,
                                                   float* __restrict__ T)
{
    __shared__ float2 U[16*256 + 16];   // U[n][g] = <n|U|g,0000>, padded
    __shared__ float2 XA[2][256];
    __shared__ float2 XB[2][256];

    const int tid  = (int)threadIdx.x;
    const int lane = tid & 63;
    const int g    = (tid >> 6) * 4 + (lane >> 4);   // circuit = basis state 0..15

    // Phase A: 16 basis-state sims through the entangler
    float sr[16], si[16];
#pragma unroll
    for (int r = 0; r < 16; ++r) {
        sr[r] = (((lane & 15) == 0) && (r == g)) ? 1.f : 0.f;
        si[r] = 0.f;
    }
    entangler(sr, si, w, lane);

#pragma unroll
    for (int r = 0; r < 16; ++r) {
        const int n = ((lane & 15) << 4) | r;
        U[uidx(n, g)] = make_float2(sr[r], si[r]);
    }
    __syncthreads();

    // Phase B: M_q[r,r'] = sum_n sign_q(n) conj(U[n,r]) U[n,r']
    {
        const int rr = tid >> 4, rp = tid & 15;
        float2 a0={0,0}, a1={0,0}, a2={0,0}, a3={0,0};
        for (int n = 0; n < 256; n += 4) {
#pragma unroll
            for (int cls = 0; cls < 4; ++cls) {
                const float2 ur = U[uidx(n+cls, rr)];
                const float2 up = U[uidx(n+cls, rp)];
                const float cre = ur.x*up.x + ur.y*up.y;
                const float cim = ur.x*up.y - ur.y*up.x;
                if      (cls==0) { a0.x += cre; a0.y += cim; }
                else if (cls==1) { a1.x += cre; a1.y += cim; }
                else if (cls==2) { a2.x += cre; a2.y += cim; }
                else             { a3.x += cre; a3.y += cim; }
            }
        }
        // q=0: sign by bit0 of n; q=1: sign by bit1 of n
        const float2 m0 = make_float2((a0.x - a1.x) + (a2.x - a3.x),
                                      (a0.y - a1.y) + (a2.y - a3.y));
        const float2 m1 = make_float2((a0.x + a1.x) - (a2.x + a3.x),
                                      (a0.y + a1.y) - (a2.y + a3.y));
        // interleave bits: idx bit(2k+1)=bit k of r (bra), bit(2k)=bit k of r' (ket)
        int idx = 0;
#pragma unroll
        for (int k = 0; k < 4; ++k)
            idx |= (((rr>>k)&1) << (2*k+1)) | (((rp>>k)&1) << (2*k));
        XA[0][idx] = m0;
        XA[1][idx] = m1;
    }
    __syncthreads();

    // Phase C: Pauli transform along each of the 4 qubit axes.
    // 2-bit field at position 2k: in = pair (a,b), out = pauli {0:I,1:X,2:Y,3:Z}
    float2 (*A)[256] = XA;
    float2 (*B)[256] = XB;
    for (int k = 0; k < 4; ++k) {
        if (tid < 128) {
            const int q = tid >> 6, quad = tid & 63;
            const int st = 1 << (2*k);
            const int ml = st - 1;
            const int base = (quad & ml) | ((quad & ~ml) << 2);
            const float2 i00 = A[q][base],      i01 = A[q][base+st];
            const float2 i10 = A[q][base+2*st], i11 = A[q][base+3*st];
            B[q][base]      = make_float2(0.5f*(i00.x+i11.x), 0.5f*(i00.y+i11.y)); // I
            B[q][base+st]   = make_float2(0.5f*(i01.x+i10.x), 0.5f*(i01.y+i10.y)); // X
            B[q][base+2*st] = make_float2(-0.5f*(i01.y-i10.y), 0.5f*(i01.x-i10.x)); // Y = i(m01-m10)/2
            B[q][base+3*st] = make_float2(0.5f*(i00.x-i11.x), 0.5f*(i00.y-i11.y)); // Z
        }
        __syncthreads();
        float2 (*t)[256] = A; A = B; B = t;
    }
    // after 4 swaps result is back in XA (== A)

    // Phase D: extract {I,Y,Z}^4 coefficients (real parts)
    if (tid < 162) {
        const int q = tid / 81, u = tid % 81;
        const int i0 = u % 3, i1 = (u/3) % 3, i2 = (u/9) % 3, i3 = u / 27;
        const int p0 = (i0==0)?0:(i0+1);   // 0->I(0), 1->Y(2), 2->Z(3)
        const int p1 = (i1==0)?0:(i1+1);
        const int p2 = (i2==0)?0:(i2+1);
        const int p3 = (i3==0)?0:(i3+1);
        const int idx = p0 | (p1<<2) | (p2<<4) | (p3<<6);
        T[tid] = A[q][idx].x;
    }
}

// ---------------- main: per-pixel tensor contraction ----------------
#define NPIX (8*39*39)   // 12168

__global__ __launch_bounds__(256) void quanv_main(const float* __restrict__ x,
                                                  const float* __restrict__ T,
                                                  float* __restrict__ out)
{
    __shared__ float Ts[162];
    const int tid = (int)threadIdx.x;
    if (tid < 162) Ts[tid] = T[tid];
    __syncthreads();

    const int gid = (int)blockIdx.x * 256 + tid;
    if (gid >= NPIX) return;

    const int j  = gid % 39;
    const int t2 = gid / 39;
    const int i  = t2 % 39;
    const int b  = t2 / 39;

    // v_k per channel: vy = -sin f_k, vz = cos f_k (full angle)
    float vy[3][4], vz[3][4];
#pragma unroll
    for (int c = 0; c < 3; ++c) {
        const float* xp = x + (((b*3 + c)*40) + i)*40 + j;
        const float f0 = xp[0], f1 = xp[1], f2 = xp[40], f3 = xp[41];
        float s, co;
        __sincosf(f0, &s, &co); vy[c][0] = -s; vz[c][0] = co;
        __sincosf(f1, &s, &co); vy[c][1] = -s; vz[c][1] = co;
        __sincosf(f2, &s, &co); vy[c][2] = -s; vz[c][2] = co;
        __sincosf(f3, &s, &co); vy[c][3] = -s; vz[c][3] = co;
    }

    float res[2];
#pragma unroll
    for (int q = 0; q < 2; ++q) {
        const float* Tq = Ts + q*81;
        float a3[3] = {0.f, 0.f, 0.f};
#pragma unroll
        for (int i3 = 0; i3 < 3; ++i3) {
            float a2[3] = {0.f, 0.f, 0.f};
#pragma unroll
            for (int i2 = 0; i2 < 3; ++i2) {
                float a1[3] = {0.f, 0.f, 0.f};
#pragma unroll
                for (int i1 = 0; i1 < 3; ++i1) {
                    const int base = ((i3*3 + i2)*3 + i1)*3;
                    const float t0 = Tq[base], t1 = Tq[base+1], t2v = Tq[base+2];
#pragma unroll
                    for (int c = 0; c < 3; ++c) {
                        const float s = fmaf(t2v, vz[c][0], fmaf(t1, vy[c][0], t0));
                        if      (i1 == 0) a1[c] += s;
                        else if (i1 == 1) a1[c] = fmaf(s, vy[c][1], a1[c]);
                        else              a1[c] = fmaf(s, vz[c][1], a1[c]);
                    }
                }
#pragma unroll
                for (int c = 0; c < 3; ++c) {
                    if      (i2 == 0) a2[c] += a1[c];
                    else if (i2 == 1) a2[c] = fmaf(a1[c], vy[c][2], a2[c]);
                    else              a2[c] = fmaf(a1[c], vz[c][2], a2[c]);
                }
            }
#pragma unroll
            for (int c = 0; c < 3; ++c) {
                if      (i3 == 0) a3[c] += a2[c];
                else if (i3 == 1) a3[c] = fmaf(a2[c], vy[c][3], a3[c]);
                else              a3[c] = fmaf(a2[c], vz[c][3], a3[c]);
            }
        }
        res[q] = (a3[0] + a3[1] + a3[2]) * (1.f/3.f);
    }

    out[((b*2 + 0)*39 + i)*39 + j] = res[0];
    out[((b*2 + 1)*39 + i)*39 + j] = res[1];
}

extern "C" void kernel_launch(void* const* d_in, const int* in_sizes, int n_in,
                              void* d_out, int out_size, void* d_ws, size_t ws_size,
                              hipStream_t stream) {
    const float* x = (const float*)d_in[0];
    const float* w = (const float*)d_in[1];
    float* out = (float*)d_out;
    float* T = (float*)d_ws;   // 162 floats

    quanv_setup<<<1, 256, 0, stream>>>(w, T);
    quanv_main<<<(NPIX + 255) / 256, 256, 0, stream>>>(x, T, out);
}

// Round 4
// 21.368 us; speedup vs baseline: 4.0180x; 1.0912x over previous
//
#include <hip/hip_runtime.h>

// Quanvolution, fully fused: every block recomputes the 162-coefficient
// observable tensor T from the weights in LDS (setup ~3us, parallel across
// blocks), then contracts it against per-pixel embedding vectors.
//
// z_q(f0..f3) = sum_{p in {I,Y,Z}^4} T_q[p] * prod_k v_k(p_k),
//   v_k = (1, -sin f_k, cos f_k)   (RX(f)|0> has <X>=0).
// T_q from 16 basis-state sims of the data-independent entangler U:
//   M_q[r,r'] = <r,0000|U^dag Z_q U|r',0000> -> Pauli transform -> T_q[81].

namespace {

// ---- wave-sim gate helpers (16 local amps; qubits 0-3 local,
// ---- qubits 4-7 = lane bits 0-3; 4 circuits per wave) ----

template<int M>
__device__ __forceinline__ void rx_local(float (&sr)[16], float (&si)[16], float c, float s) {
#pragma unroll
    for (int r = 0; r < 16; ++r) {
        if (r & M) continue;
        const int a = r, b = r | M;
        float nra = c*sr[a] + s*si[b], nia = c*si[a] - s*sr[b];
        float nrb = c*sr[b] + s*si[a], nib = c*si[b] - s*sr[a];
        sr[a]=nra; si[a]=nia; sr[b]=nrb; si[b]=nib;
    }
}

__device__ __forceinline__ void rx_lane16(float (&sr)[16], float (&si)[16], float c, float s, int mask) {
#pragma unroll
    for (int r = 0; r < 16; ++r) {
        float orr = __shfl_xor(sr[r], mask, 64);
        float oii = __shfl_xor(si[r], mask, 64);
        sr[r] = c*sr[r] + s*oii;
        si[r] = c*si[r] - s*orr;
    }
}

template<int C, int T>
__device__ __forceinline__ void cnot_ll(float (&sr)[16], float (&si)[16]) {
#pragma unroll
    for (int r = 0; r < 16; ++r) {
        if (!(r & C) || (r & T)) continue;
        const int a = r, b = r ^ T;
        float tr=sr[a], ti=si[a];
        sr[a]=sr[b]; si[a]=si[b];
        sr[b]=tr;    si[b]=ti;
    }
}

__device__ __forceinline__ void entangler(float (&sr)[16], float (&si)[16],
                                          const float* __restrict__ w, int lane) {
    float c, s;
#pragma unroll
    for (int l = 0; l < 2; ++l) {
        __sincosf(0.5f*w[l*8+0], &s, &c); rx_local<1>(sr, si, c, s);
        __sincosf(0.5f*w[l*8+1], &s, &c); rx_local<2>(sr, si, c, s);
        __sincosf(0.5f*w[l*8+2], &s, &c); rx_local<4>(sr, si, c, s);
        __sincosf(0.5f*w[l*8+3], &s, &c); rx_local<8>(sr, si, c, s);
        __sincosf(0.5f*w[l*8+4], &s, &c); rx_lane16(sr, si, c, s, 1);
        __sincosf(0.5f*w[l*8+5], &s, &c); rx_lane16(sr, si, c, s, 2);
        __sincosf(0.5f*w[l*8+6], &s, &c); rx_lane16(sr, si, c, s, 4);
        __sincosf(0.5f*w[l*8+7], &s, &c); rx_lane16(sr, si, c, s, 8);

        cnot_ll<1,2>(sr, si);   // (0,1)
        cnot_ll<2,4>(sr, si);   // (1,2)
        cnot_ll<4,8>(sr, si);   // (2,3)
        // (3,4): control local b3, target lane b0
#pragma unroll
        for (int r = 8; r < 16; ++r) {
            sr[r] = __shfl_xor(sr[r], 1, 64);
            si[r] = __shfl_xor(si[r], 1, 64);
        }
        // (4,5),(5,6),(6,7)
#pragma unroll
        for (int qq = 0; qq < 3; ++qq) {
            const int mt = 2 << qq;
            const bool ctrl = (lane >> qq) & 1;
#pragma unroll
            for (int r = 0; r < 16; ++r) {
                float orr = __shfl_xor(sr[r], mt, 64);
                float oii = __shfl_xor(si[r], mt, 64);
                sr[r] = ctrl ? orr : sr[r];
                si[r] = ctrl ? oii : si[r];
            }
        }
        // (7,0): control lane b3, target local b0
        {
            const bool c7 = (lane >> 3) & 1;
#pragma unroll
            for (int r = 0; r < 16; r += 2) {
                float ar = c7 ? sr[r+1] : sr[r];
                float ai = c7 ? si[r+1] : si[r];
                float br = c7 ? sr[r]   : sr[r+1];
                float bi = c7 ? si[r]   : si[r+1];
                sr[r]=ar; si[r]=ai; sr[r+1]=br; si[r+1]=bi;
            }
        }
    }
}

__device__ __forceinline__ int uidx(int n, int g) { return n*16 + g + (n>>4); }

} // namespace

#define NPIX (8*39*39)   // 12168
#define BLK  512
#define NBLK ((NPIX + BLK - 1) / BLK)   // 24

__global__ __launch_bounds__(512) void quanv_fused(
    const float* __restrict__ x,   // (8,3,40,40)
    const float* __restrict__ w,   // (2,8)
    float* __restrict__ out)       // (8,2,39,39)
{
    __shared__ float2 U[16*256 + 16];    // U[n][g], padded
    __shared__ float2 XA[2][256];
    __shared__ float2 XB[2][256];
    __shared__ float2 PB[2][2][256];     // [half][q][pair] Gram partials
    __shared__ float  Tp[216];           // padded T: [q][27][4] = (t0,t1,t2,pad)

    const int tid  = (int)threadIdx.x;
    const int lane = tid & 63;

    // ---- issue pixel loads first; latency hides under setup ----
    const int gid = (int)blockIdx.x * BLK + tid;
    const int pid = (gid < NPIX) ? gid : (NPIX - 1);
    const int j  = pid % 39;
    const int t2 = pid / 39;
    const int i  = t2 % 39;
    const int b  = t2 / 39;

    float f[12];
#pragma unroll
    for (int c = 0; c < 3; ++c) {
        const float* xp = x + (((b*3 + c)*40) + i)*40 + j;
        f[c*4+0] = xp[0];  f[c*4+1] = xp[1];
        f[c*4+2] = xp[40]; f[c*4+3] = xp[41];
    }

    // ---- Phase A: 16 basis-state sims (waves 0-3 only) ----
    if (tid < 256) {
        const int g = (tid >> 6) * 4 + (lane >> 4);
        float sr[16], si[16];
#pragma unroll
        for (int r = 0; r < 16; ++r) {
            sr[r] = (((lane & 15) == 0) && (r == g)) ? 1.f : 0.f;
            si[r] = 0.f;
        }
        entangler(sr, si, w, lane);
#pragma unroll
        for (int r = 0; r < 16; ++r) {
            const int n = ((lane & 15) << 4) | r;
            U[uidx(n, g)] = make_float2(sr[r], si[r]);
        }
    }
    __syncthreads();

    // ---- Phase B: Gram partials, n-sum split 2-way ----
    {
        const int pair = tid & 255;
        const int h    = tid >> 8;
        const int rr = pair >> 4, rp = pair & 15;
        float2 a0={0,0}, a1={0,0}, a2={0,0}, a3={0,0};
        const int n0 = h * 128;
        for (int n = n0; n < n0 + 128; n += 4) {
#pragma unroll
            for (int cls = 0; cls < 4; ++cls) {
                const float2 ur = U[uidx(n+cls, rr)];
                const float2 up = U[uidx(n+cls, rp)];
                const float cre = ur.x*up.x + ur.y*up.y;
                const float cim = ur.x*up.y - ur.y*up.x;
                if      (cls==0) { a0.x += cre; a0.y += cim; }
                else if (cls==1) { a1.x += cre; a1.y += cim; }
                else if (cls==2) { a2.x += cre; a2.y += cim; }
                else             { a3.x += cre; a3.y += cim; }
            }
        }
        PB[h][0][pair] = make_float2((a0.x - a1.x) + (a2.x - a3.x),
                                     (a0.y - a1.y) + (a2.y - a3.y));
        PB[h][1][pair] = make_float2((a0.x + a1.x) - (a2.x + a3.x),
                                     (a0.y + a1.y) - (a2.y + a3.y));
    }
    __syncthreads();

    // ---- combine halves + bit-interleave into XA ----
    if (tid < 256) {
        const int rr = tid >> 4, rp = tid & 15;
        int idx = 0;
#pragma unroll
        for (int k = 0; k < 4; ++k)
            idx |= (((rr>>k)&1) << (2*k+1)) | (((rp>>k)&1) << (2*k));
#pragma unroll
        for (int q = 0; q < 2; ++q) {
            const float2 pa = PB[0][q][tid], pb = PB[1][q][tid];
            XA[q][idx] = make_float2(pa.x + pb.x, pa.y + pb.y);
        }
    }
    __syncthreads();

    // ---- Phase C: Pauli transform along 4 qubit axes ----
    float2 (*A)[256] = XA;
    float2 (*B)[256] = XB;
    for (int k = 0; k < 4; ++k) {
        if (tid < 128) {
            const int q = tid >> 6, quad = tid & 63;
            const int st = 1 << (2*k);
            const int ml = st - 1;
            const int base = (quad & ml) | ((quad & ~ml) << 2);
            const float2 i00 = A[q][base],      i01 = A[q][base+st];
            const float2 i10 = A[q][base+2*st], i11 = A[q][base+3*st];
            B[q][base]      = make_float2(0.5f*(i00.x+i11.x), 0.5f*(i00.y+i11.y)); // I
            B[q][base+st]   = make_float2(0.5f*(i01.x+i10.x), 0.5f*(i01.y+i10.y)); // X
            B[q][base+2*st] = make_float2(-0.5f*(i01.y-i10.y), 0.5f*(i01.x-i10.x)); // Y
            B[q][base+3*st] = make_float2(0.5f*(i00.x-i11.x), 0.5f*(i00.y-i11.y)); // Z
        }
        __syncthreads();
        float2 (*t)[256] = A; A = B; B = t;
    }

    // ---- Phase D: extract {I,Y,Z}^4 real coefficients, padded float4 ----
    if (tid < 162) {
        const int q = tid / 81, u = tid % 81;
        const int i0 = u % 3, i1 = (u/3) % 3, i2 = (u/9) % 3, i3 = u / 27;
        const int p0 = (i0==0)?0:(i0+1);
        const int p1 = (i1==0)?0:(i1+1);
        const int p2 = (i2==0)?0:(i2+1);
        const int p3 = (i3==0)?0:(i3+1);
        const int idx = p0 | (p1<<2) | (p2<<4) | (p3<<6);
        Tp[q*108 + (u/3)*4 + i0] = A[q][idx].x;
    }
    __syncthreads();

    // ---- main: per-pixel contraction ----
    if (gid < NPIX) {
        float vy[3][4], vz[3][4];
#pragma unroll
        for (int c = 0; c < 3; ++c) {
#pragma unroll
            for (int k = 0; k < 4; ++k) {
                float s, co;
                __sincosf(f[c*4+k], &s, &co);
                vy[c][k] = -s; vz[c][k] = co;
            }
        }

        float res[2];
#pragma unroll
        for (int q = 0; q < 2; ++q) {
            float a3[3] = {0.f, 0.f, 0.f};
#pragma unroll
            for (int i3 = 0; i3 < 3; ++i3) {
                float a2[3] = {0.f, 0.f, 0.f};
#pragma unroll
                for (int i2 = 0; i2 < 3; ++i2) {
                    float a1[3] = {0.f, 0.f, 0.f};
#pragma unroll
                    for (int i1 = 0; i1 < 3; ++i1) {
                        const float4 tv = *reinterpret_cast<const float4*>(
                            &Tp[q*108 + ((i3*3 + i2)*3 + i1)*4]);
#pragma unroll
                        for (int c = 0; c < 3; ++c) {
                            const float s = fmaf(tv.z, vz[c][0], fmaf(tv.y, vy[c][0], tv.x));
                            if      (i1 == 0) a1[c] += s;
                            else if (i1 == 1) a1[c] = fmaf(s, vy[c][1], a1[c]);
                            else              a1[c] = fmaf(s, vz[c][1], a1[c]);
                        }
                    }
#pragma unroll
                    for (int c = 0; c < 3; ++c) {
                        if      (i2 == 0) a2[c] += a1[c];
                        else if (i2 == 1) a2[c] = fmaf(a1[c], vy[c][2], a2[c]);
                        else              a2[c] = fmaf(a1[c], vz[c][2], a2[c]);
                    }
                }
#pragma unroll
                for (int c = 0; c < 3; ++c) {
                    if      (i3 == 0) a3[c] += a2[c];
                    else if (i3 == 1) a3[c] = fmaf(a2[c], vy[c][3], a3[c]);
                    else              a3[c] = fmaf(a2[c], vz[c][3], a3[c]);
                }
            }
            res[q] = (a3[0] + a3[1] + a3[2]) * (1.f/3.f);
        }

        out[((b*2 + 0)*39 + i)*39 + j] = res[0];
        out[((b*2 + 1)*39 + i)*39 + j] = res[1];
    }
}

extern "C" void kernel_launch(void* const* d_in, const int* in_sizes, int n_in,
                              void* d_out, int out_size, void* d_ws, size_t ws_size,
                              hipStream_t stream) {
    const float* x = (const float*)d_in[0];
    const float* w = (const float*)d_in[1];
    float* out = (float*)d_out;

    quanv_fused<<<NBLK, BLK, 0, stream>>>(x, w, out);
}

// Round 5
// 20.838 us; speedup vs baseline: 4.1201x; 1.0254x over previous
//
#include <hip/hip_runtime.h>

// Quanvolution, fused: every block recomputes the 162-coefficient observable
// tensor T from the weights in LDS, then contracts per-pixel.
//   z_q(f0..f3) = sum_{p in {I,Y,Z}^4} T_q[p] * prod_k v_k(p_k),
//   v_k = (1, -sin f_k, cos f_k)   (RX(f)|0> has <X>=0).
// T_q from 16 basis-state sims of the data-independent entangler U:
//   M_q[r,r'] = <r,0000|U^dag Z_q U|r',0000> (Hermitian -> 136 pairs)
//   -> Pauli transform -> T_q[81] (1/3 channel-mean folded in).

namespace {

template<int M>
__device__ __forceinline__ void rx_local(float (&sr)[16], float (&si)[16], float c, float s) {
#pragma unroll
    for (int r = 0; r < 16; ++r) {
        if (r & M) continue;
        const int a = r, b = r | M;
        float nra = c*sr[a] + s*si[b], nia = c*si[a] - s*sr[b];
        float nrb = c*sr[b] + s*si[a], nib = c*si[b] - s*sr[a];
        sr[a]=nra; si[a]=nia; sr[b]=nrb; si[b]=nib;
    }
}

__device__ __forceinline__ void rx_lane16(float (&sr)[16], float (&si)[16], float c, float s, int mask) {
#pragma unroll
    for (int r = 0; r < 16; ++r) {
        float orr = __shfl_xor(sr[r], mask, 64);
        float oii = __shfl_xor(si[r], mask, 64);
        sr[r] = c*sr[r] + s*oii;
        si[r] = c*si[r] - s*orr;
    }
}

template<int C, int T>
__device__ __forceinline__ void cnot_ll(float (&sr)[16], float (&si)[16]) {
#pragma unroll
    for (int r = 0; r < 16; ++r) {
        if (!(r & C) || (r & T)) continue;
        const int a = r, b = r ^ T;
        float tr=sr[a], ti=si[a];
        sr[a]=sr[b]; si[a]=si[b];
        sr[b]=tr;    si[b]=ti;
    }
}

__device__ __forceinline__ void entangler(float (&sr)[16], float (&si)[16],
                                          const float* __restrict__ w, int lane) {
    float c, s;
#pragma unroll
    for (int l = 0; l < 2; ++l) {
        __sincosf(0.5f*w[l*8+0], &s, &c); rx_local<1>(sr, si, c, s);
        __sincosf(0.5f*w[l*8+1], &s, &c); rx_local<2>(sr, si, c, s);
        __sincosf(0.5f*w[l*8+2], &s, &c); rx_local<4>(sr, si, c, s);
        __sincosf(0.5f*w[l*8+3], &s, &c); rx_local<8>(sr, si, c, s);
        __sincosf(0.5f*w[l*8+4], &s, &c); rx_lane16(sr, si, c, s, 1);
        __sincosf(0.5f*w[l*8+5], &s, &c); rx_lane16(sr, si, c, s, 2);
        __sincosf(0.5f*w[l*8+6], &s, &c); rx_lane16(sr, si, c, s, 4);
        __sincosf(0.5f*w[l*8+7], &s, &c); rx_lane16(sr, si, c, s, 8);

        cnot_ll<1,2>(sr, si);   // (0,1)
        cnot_ll<2,4>(sr, si);   // (1,2)
        cnot_ll<4,8>(sr, si);   // (2,3)
#pragma unroll
        for (int r = 8; r < 16; ++r) {           // (3,4)
            sr[r] = __shfl_xor(sr[r], 1, 64);
            si[r] = __shfl_xor(si[r], 1, 64);
        }
#pragma unroll
        for (int qq = 0; qq < 3; ++qq) {         // (4,5),(5,6),(6,7)
            const int mt = 2 << qq;
            const bool ctrl = (lane >> qq) & 1;
#pragma unroll
            for (int r = 0; r < 16; ++r) {
                float orr = __shfl_xor(sr[r], mt, 64);
                float oii = __shfl_xor(si[r], mt, 64);
                sr[r] = ctrl ? orr : sr[r];
                si[r] = ctrl ? oii : si[r];
            }
        }
        {                                         // (7,0)
            const bool c7 = (lane >> 3) & 1;
#pragma unroll
            for (int r = 0; r < 16; r += 2) {
                float ar = c7 ? sr[r+1] : sr[r];
                float ai = c7 ? si[r+1] : si[r];
                float br = c7 ? sr[r]   : sr[r+1];
                float bi = c7 ? si[r]   : si[r+1];
                sr[r]=ar; si[r]=ai; sr[r+1]=br; si[r+1]=bi;
            }
        }
    }
}

__device__ __forceinline__ int uidx(int n, int g) { return n*16 + g + (n>>4); }

__device__ __forceinline__ void tri_decode(int t, int& rr, int& rp) {
    int r = 0, rem = t;
    while (rem >= 16 - r) { rem -= 16 - r; ++r; }
    rr = r; rp = r + rem;
}

__device__ __forceinline__ int ilv(int bra, int ket) {
    int idx = 0;
#pragma unroll
    for (int k = 0; k < 4; ++k)
        idx |= (((bra>>k)&1) << (2*k+1)) | (((ket>>k)&1) << (2*k));
    return idx;
}

} // namespace

#define NPIX (8*39*39)   // 12168
#define BLK  1024
#define PPB  512
#define NBLK ((NPIX + PPB - 1) / PPB)   // 24

__global__ __launch_bounds__(1024) void quanv_fused(
    const float* __restrict__ x,   // (8,3,40,40)
    const float* __restrict__ w,   // (2,8)
    float* __restrict__ out)       // (8,2,39,39)
{
    __shared__ float2 U[16*256 + 16];    // U[n][g], padded
    __shared__ float2 XA[2][256];
    __shared__ float2 XB[2][256];
    __shared__ float2 PB[4][2][136];     // [quarter][q][pair] Gram partials
    __shared__ __align__(16) float Tp[216];  // [q][27][4] = (t0,t1,t2,pad)

    const int tid  = (int)threadIdx.x;
    const int lane = tid & 63;

    // ---- pixel/q decode; issue loads early (latency hides under setup) ----
    const int half = tid >> 9;            // output qubit q for contraction
    const int gpix = (int)blockIdx.x * PPB + (tid & 511);
    const int pid  = (gpix < NPIX) ? gpix : (NPIX - 1);
    const int j  = pid % 39;
    const int t2 = pid / 39;
    const int i  = t2 % 39;
    const int b  = t2 / 39;

    float f[12];
#pragma unroll
    for (int c = 0; c < 3; ++c) {
        const float* xp = x + (((b*3 + c)*40) + i)*40 + j;
        f[c*4+0] = xp[0];  f[c*4+1] = xp[1];
        f[c*4+2] = xp[40]; f[c*4+3] = xp[41];
    }

    // ---- Phase A: 16 basis-state sims (waves 0-3) ----
    if (tid < 256) {
        const int g = (tid >> 6) * 4 + (lane >> 4);
        float sr[16], si[16];
#pragma unroll
        for (int r = 0; r < 16; ++r) {
            sr[r] = (((lane & 15) == 0) && (r == g)) ? 1.f : 0.f;
            si[r] = 0.f;
        }
        entangler(sr, si, w, lane);
#pragma unroll
        for (int r = 0; r < 16; ++r) {
            const int n = ((lane & 15) << 4) | r;
            U[uidx(n, g)] = make_float2(sr[r], si[r]);
        }
    }
    __syncthreads();

    // ---- Phase B: Hermitian Gram partials, 136 pairs x 4-way n-split ----
    if (tid < 544) {
        const int t = tid >> 2, quarter = tid & 3;
        int rr, rp; tri_decode(t, rr, rp);
        float2 a0={0,0}, a1={0,0}, a2={0,0}, a3={0,0};
        const int n0 = quarter * 64;
        for (int n = n0; n < n0 + 64; n += 4) {
#pragma unroll
            for (int cls = 0; cls < 4; ++cls) {
                const float2 ur = U[uidx(n+cls, rr)];
                const float2 up = U[uidx(n+cls, rp)];
                const float cre = ur.x*up.x + ur.y*up.y;
                const float cim = ur.x*up.y - ur.y*up.x;
                if      (cls==0) { a0.x += cre; a0.y += cim; }
                else if (cls==1) { a1.x += cre; a1.y += cim; }
                else if (cls==2) { a2.x += cre; a2.y += cim; }
                else             { a3.x += cre; a3.y += cim; }
            }
        }
        PB[quarter][0][t] = make_float2((a0.x - a1.x) + (a2.x - a3.x),
                                        (a0.y - a1.y) + (a2.y - a3.y));
        PB[quarter][1][t] = make_float2((a0.x + a1.x) - (a2.x + a3.x),
                                        (a0.y + a1.y) - (a2.y + a3.y));
    }
    __syncthreads();

    // ---- combine quarters + Hermitian mirror + bit-interleave ----
    if (tid < 136) {
        int rr, rp; tri_decode(tid, rr, rp);
        const int idx  = ilv(rr, rp);
        const int idxT = ilv(rp, rr);
#pragma unroll
        for (int q = 0; q < 2; ++q) {
            float2 m = PB[0][q][tid];
            m.x += PB[1][q][tid].x + PB[2][q][tid].x + PB[3][q][tid].x;
            m.y += PB[1][q][tid].y + PB[2][q][tid].y + PB[3][q][tid].y;
            XA[q][idxT] = make_float2(m.x, -m.y);
            XA[q][idx]  = m;
        }
    }
    __syncthreads();

    // ---- Phase C: Pauli transform along 4 qubit axes ----
    float2 (*A)[256] = XA;
    float2 (*B)[256] = XB;
    for (int k = 0; k < 4; ++k) {
        if (tid < 128) {
            const int q = tid >> 6, quad = tid & 63;
            const int st = 1 << (2*k);
            const int ml = st - 1;
            const int base = (quad & ml) | ((quad & ~ml) << 2);
            const float2 i00 = A[q][base],      i01 = A[q][base+st];
            const float2 i10 = A[q][base+2*st], i11 = A[q][base+3*st];
            B[q][base]      = make_float2(0.5f*(i00.x+i11.x), 0.5f*(i00.y+i11.y)); // I
            B[q][base+st]   = make_float2(0.5f*(i01.x+i10.x), 0.5f*(i01.y+i10.y)); // X
            B[q][base+2*st] = make_float2(-0.5f*(i01.y-i10.y), 0.5f*(i01.x-i10.x)); // Y
            B[q][base+3*st] = make_float2(0.5f*(i00.x-i11.x), 0.5f*(i00.y-i11.y)); // Z
        }
        __syncthreads();
        float2 (*t)[256] = A; A = B; B = t;
    }

    // ---- Phase D: extract {I,Y,Z}^4 real coefficients (1/3 folded) ----
    if (tid < 162) {
        const int q = tid / 81, u = tid % 81;
        const int i0 = u % 3, i1 = (u/3) % 3, i2 = (u/9) % 3, i3 = u / 27;
        const int p0 = (i0==0)?0:(i0+1);
        const int p1 = (i1==0)?0:(i1+1);
        const int p2 = (i2==0)?0:(i2+1);
        const int p3 = (i3==0)?0:(i3+1);
        const int idx = p0 | (p1<<2) | (p2<<4) | (p3<<6);
        Tp[q*108 + (u/3)*4 + i0] = A[q][idx].x * (1.f/3.f);
    }
    __syncthreads();

    // ---- contraction: one (pixel, q) per thread ----
    if (gpix < NPIX) {
        float vy[3][4], vz[3][4];
#pragma unroll
        for (int c = 0; c < 3; ++c) {
#pragma unroll
            for (int k = 0; k < 4; ++k) {
                float s, co;
                __sincosf(f[c*4+k], &s, &co);
                vy[c][k] = -s; vz[c][k] = co;
            }
        }

        float a3[3] = {0.f, 0.f, 0.f};
#pragma unroll
        for (int i3 = 0; i3 < 3; ++i3) {
            float a2[3] = {0.f, 0.f, 0.f};
#pragma unroll
            for (int i2 = 0; i2 < 3; ++i2) {
                float a1[3] = {0.f, 0.f, 0.f};
#pragma unroll
                for (int i1 = 0; i1 < 3; ++i1) {
                    const float4 tv = *reinterpret_cast<const float4*>(
                        &Tp[half*108 + ((i3*3 + i2)*3 + i1)*4]);
#pragma unroll
                    for (int c = 0; c < 3; ++c) {
                        const float s = fmaf(tv.z, vz[c][0], fmaf(tv.y, vy[c][0], tv.x));
                        if      (i1 == 0) a1[c] += s;
                        else if (i1 == 1) a1[c] = fmaf(s, vy[c][1], a1[c]);
                        else              a1[c] = fmaf(s, vz[c][1], a1[c]);
                    }
                }
#pragma unroll
                for (int c = 0; c < 3; ++c) {
                    if      (i2 == 0) a2[c] += a1[c];
                    else if (i2 == 1) a2[c] = fmaf(a1[c], vy[c][2], a2[c]);
                    else              a2[c] = fmaf(a1[c], vz[c][2], a2[c]);
                }
            }
#pragma unroll
            for (int c = 0; c < 3; ++c) {
                if      (i3 == 0) a3[c] += a2[c];
                else if (i3 == 1) a3[c] = fmaf(a2[c], vy[c][3], a3[c]);
                else              a3[c] = fmaf(a2[c], vz[c][3], a3[c]);
            }
        }

        out[((b*2 + half)*39 + i)*39 + j] = a3[0] + a3[1] + a3[2];
    }
}

extern "C" void kernel_launch(void* const* d_in, const int* in_sizes, int n_in,
                              void* d_out, int out_size, void* d_ws, size_t ws_size,
                              hipStream_t stream) {
    const float* x = (const float*)d_in[0];
    const float* w = (const float*)d_in[1];
    float* out = (float*)d_out;

    quanv_fused<<<NBLK, BLK, 0, stream>>>(x, w, out);
}